// Round 13
// baseline (703.777 us; speedup 1.0000x reference)
//
#include <hip/hip_runtime.h>
#include <hip/hip_bf16.h>

#define NNODES 331776            // 81 * 4096
#define NGRAPH 4096
#define NBUCK  2048              // buckets
#define BNODES 162               // nodes per bucket (2048*162 == 331776)
#define TE     4096              // edges per tile (977 blocks -> ~4/CU; 16384 gave 245 blocks = 7% occupancy)
#define CAP    2560              // max edges/bucket (lambda=1953, 13.7 sigma)

typedef __attribute__((ext_vector_type(8))) short bf8;   // 8 bf16 (4 VGPR)
typedef __attribute__((ext_vector_type(4))) float f4;    // 4 fp32 acc

static __device__ __forceinline__ short f2bf(float x) {
    return (short)__builtin_bit_cast(unsigned short, __float2bfloat16(x));
}
static __device__ __forceinline__ float bf2f(unsigned short u) {
    return __bfloat162float(__hip_bfloat16_raw{u});
}

// ---------------- deterministic bucket sort (no global atomics) ----------------

__global__ __launch_bounds__(256) void k_hist(const int* __restrict__ dst,
                                              int* __restrict__ H, int E) {
    __shared__ int h[NBUCK];
    int t = threadIdx.x, b = blockIdx.x;
    for (int i = t; i < NBUCK; i += 256) h[i] = 0;
    __syncthreads();
    int lo = b * TE, hi = min(E, lo + TE);
    for (int e = lo + t; e < hi; e += 256)
        atomicAdd(&h[dst[e] / BNODES], 1);
    __syncthreads();
    for (int i = t; i < NBUCK; i += 256) H[b * NBUCK + i] = h[i];
}

// per-bucket exclusive scan across tiles (in place); T[bin] = total
__global__ void k_colscan(int* __restrict__ H, int* __restrict__ T, int NT) {
    int bin = blockIdx.x * 256 + threadIdx.x;
    int s = 0;
    for (int t = 0; t < NT; t++) {
        int v = H[t * NBUCK + bin];
        H[t * NBUCK + bin] = s;
        s += v;
    }
    T[bin] = s;
}

// exclusive scan over the 2048 bucket totals -> Bstart[0..NBUCK]
__global__ __launch_bounds__(256) void k_binscan(const int* __restrict__ T,
                                                 int* __restrict__ Bstart) {
    __shared__ int tmp[256];
    int t = threadIdx.x;
    int base = t * 8;
    int loc[8]; int s = 0;
#pragma unroll
    for (int i = 0; i < 8; i++) { loc[i] = s; s += T[base + i]; }
    tmp[t] = s; __syncthreads();
    for (int o = 1; o < 256; o <<= 1) {
        int a = (t >= o) ? tmp[t - o] : 0;
        __syncthreads();
        tmp[t] += a;
        __syncthreads();
    }
    int excl = tmp[t] - s;
#pragma unroll
    for (int i = 0; i < 8; i++) Bstart[base + i] = excl + loc[i];
    if (t == 255) Bstart[NBUCK] = excl + s;
}

// place edges into bucket-major order; payload packs (src | dst_local<<19, esig)
// esig = sign(w)*exp(|w|) computed once here (sign consumed by k_sortbucket).
__global__ __launch_bounds__(256) void k_place(
    const int* __restrict__ src, const int* __restrict__ dst,
    const float* __restrict__ w,
    const int* __restrict__ H, const int* __restrict__ Bstart,
    int2* __restrict__ csrB, int E) {
    __shared__ int cur[NBUCK];
    int t = threadIdx.x, b = blockIdx.x;
    for (int i = t; i < NBUCK; i += 256)
        cur[i] = Bstart[i] + H[b * NBUCK + i];
    __syncthreads();
    int lo = b * TE, hi = min(E, lo + TE);
    for (int e = lo + t; e < hi; e += 256) {
        int d  = dst[e];
        int sx = src[e];
        float wv = w[e];
        float es = 0.f;
        if (wv > 0.f)      es = __expf(wv);
        else if (wv < 0.f) es = -__expf(-wv);
        int bin = d / BNODES;
        int dl  = d - bin * BNODES;
        int p = atomicAdd(&cur[bin], 1);        // LDS atomic; same-bin runs -> consecutive p
        int2 pk;
        pk.x = sx | (dl << 19);
        pk.y = __float_as_int(es);
        csrB[p] = pk;
    }
}

// per-bucket counting sort (in place), key = dst_local*2 + sign:
// each node's edges land [positives | negatives], payload stores |es|.
// Emits cnt[] (total), cntp[] (positive count), offs[] (start).
__global__ __launch_bounds__(256) void k_sortbucket(
    int2* __restrict__ csrB, const int* __restrict__ Bstart,
    int* __restrict__ cnt, int* __restrict__ cntp, int* __restrict__ offs) {
    __shared__ int2 pb[CAP];
    __shared__ int lcnt[BNODES * 2];
    __shared__ int lpos[BNODES * 2];
    int t = threadIdx.x, b = blockIdx.x;
    int lo = Bstart[b];
    int S  = Bstart[b + 1] - lo;
    if (S > CAP) S = CAP;                        // memory-safety guard (never expected)
    for (int i = t; i < BNODES * 2; i += 256) lcnt[i] = 0;
    __syncthreads();
    for (int i = t; i < S; i += 256) {
        int2 pk = csrB[lo + i];                  // coalesced
        pb[i] = pk;
        int key = ((pk.x >> 19) << 1) | ((unsigned)pk.y >> 31);
        atomicAdd(&lcnt[key], 1);
    }
    __syncthreads();
    if (t == 0) {
        int s = 0;
        for (int i = 0; i < BNODES * 2; i++) { lpos[i] = s; s += lcnt[i]; }
    }
    __syncthreads();
    int node0 = b * BNODES;
    for (int i = t; i < BNODES; i += 256) {
        cnt[node0 + i]  = lcnt[2 * i] + lcnt[2 * i + 1];
        cntp[node0 + i] = lcnt[2 * i];
        offs[node0 + i] = lo + lpos[2 * i];
    }
    __syncthreads();
    for (int i = t; i < S; i += 256) {
        int2 pk = pb[i];
        int key = ((pk.x >> 19) << 1) | ((unsigned)pk.y >> 31);
        int p = atomicAdd(&lpos[key], 1);
        int2 outv;
        outv.x = pk.x & 0x7FFFF;                 // unpacked src
        outv.y = pk.y & 0x7FFFFFFF;              // |es| (sign now positional)
        csrB[lo + p] = outv;                     // bucket-local, L2-hot
    }
}

// ---------------- Layer 1 (h0 = deg, 1 feature -> 32), bf16 output ----------
// Magnitude payload; sign from position (j+f < np).

__global__ __launch_bounds__(256) void k_layer1(
    const int* __restrict__ cnt, const int* __restrict__ cntp,
    const int* __restrict__ offs, const int2* __restrict__ csr,
    float* __restrict__ spos, float* __restrict__ sneg,
    unsigned short* __restrict__ h1b,
    const float* __restrict__ W1, const float* __restrict__ b1,
    const float* __restrict__ bias1,
    const float* __restrict__ c1s, const float* __restrict__ c1p,
    const float* __restrict__ c1n) {
    int t = threadIdx.x;
    int g = t >> 5, f = t & 31;
    int d = blockIdx.x * 8 + g;
    int beg = offs[d];
    int len = cnt[d];
    int np  = cntp[d];
    float sp = 0.f, sn = 0.f, up = 0.f, un = 0.f;
    for (int j = 0; j < len; j += 32) {
        int rem = len - j;
        if (f < rem) {
            int2 sw = csr[beg + j + f];            // coalesced 8B/lane
            float es = __int_as_float(sw.y);        // |es|
            float degs = (float)cnt[sw.x];          // parallel gather, L2-hot
            float ep = (j + f < np) ? es : 0.f;
            float en = es - ep;
            sp += ep; sn += en;
            up = fmaf(degs, ep, up); un = fmaf(degs, en, un);
        }
    }
    for (int m = 16; m; m >>= 1) {
        sp += __shfl_xor(sp, m, 32);
        sn += __shfl_xor(sn, m, 32);
        up += __shfl_xor(up, m, 32);
        un += __shfl_xor(un, m, 32);
    }
    if (f == 0) { spos[d] = sp; sneg[d] = sn; }
    float hp = up / fmaxf(sp, 1e-20f);
    float hn = un / fmaxf(sn, 1e-20f);
    float x0 = c1s[0] * (float)len;   // deg[d] == len
    float x1 = c1p[0] * hp;
    float x2 = c1n[0] * hn;
    float v = W1[f * 3] * x0 + W1[f * 3 + 1] * x1 + W1[f * 3 + 2] * x2
            + b1[f] + bias1[f];
    v = fmaxf(v, 0.f);
    h1b[d * 32 + f] = (unsigned short)f2bf(v);      // bf16 table (gathered + MFMA A)
}

// ---------------- Layer-2 aggregation ----------------------------------------
// Half-wave per node; sign-partitioned ranges: 2 shuffles + 1 fma + 1 cvt per
// edge, zero sign logic (pads get e=0 via the range guard; sx=0 pads hit the
// L1-hot node-0 line). 8-deep gather batches keep loads in flight.

static __device__ __forceinline__ float range_accum(
    const int2* __restrict__ csr, const unsigned short* __restrict__ h1b,
    int rbeg, int count, int f) {
    float a = 0.f;
    for (int j = 0; j < count; j += 32) {
        int rem = count - j;
        int sx = 0;
        float e = 0.f;
        if (f < rem) {
            int2 pk = csr[rbeg + j + f];           // coalesced 8B/lane
            sx = pk.x;
            e = __int_as_float(pk.y);              // |es|
        }
        int n = rem < 32 ? rem : 32;
        for (int q = 0; q < n; q += 8) {
            float ev[8], hv[8];
#pragma unroll
            for (int u = 0; u < 8; u++) {
                int s = __shfl(sx, q + u, 32);
                ev[u] = __shfl(e, q + u, 32);
                hv[u] = bf2f(h1b[s * 32 + f]);     // 8 independent gathers
            }
#pragma unroll
            for (int u = 0; u < 8; u++) a = fmaf(ev[u], hv[u], a);
        }
    }
    return a;
}

__global__ __launch_bounds__(256) void k_agg(
    const int* __restrict__ cnt, const int* __restrict__ cntp,
    const int* __restrict__ offs, const int2* __restrict__ csr,
    const float* __restrict__ spos, const float* __restrict__ sneg,
    const unsigned short* __restrict__ h1b,
    unsigned short* __restrict__ hpb, unsigned short* __restrict__ hnb) {
    int t = threadIdx.x;
    int g = t >> 5, f = t & 31;
    int d = blockIdx.x * 8 + g;     // NNODES % 8 == 0
    int beg = offs[d];
    int len = cnt[d];
    int np  = cntp[d];
    float ap = range_accum(csr, h1b, beg, np, f);
    float an = range_accum(csr, h1b, beg + np, len - np, f);
    hpb[d * 32 + f] = (unsigned short)f2bf(ap / fmaxf(spos[d], 1e-20f));
    hnb[d * 32 + f] = (unsigned short)f2bf(an / fmaxf(sneg[d], 1e-20f));
}

// ---------------- weight prep: bf16 transposed, scales folded ---------------
// W2sT[k][n] = bf16(W2[n][k] * c_{k/32})   (96 x 32)
// k1T[k][o]  = bf16(k1[o][k])              (64 x 16)

__global__ __launch_bounds__(256) void k_prep(
    const float* __restrict__ W2, const float* __restrict__ c2s,
    const float* __restrict__ c2p, const float* __restrict__ c2n,
    const float* __restrict__ k1,
    unsigned short* __restrict__ W2sT, unsigned short* __restrict__ k1T) {
    int i = blockIdx.x * 256 + threadIdx.x;
    if (i < 96 * 32) {
        int k = i >> 5, n = i & 31;
        float sc = (k < 32) ? c2s[0] : ((k < 64) ? c2p[0] : c2n[0]);
        W2sT[i] = (unsigned short)f2bf(W2[n * 96 + k] * sc);
    } else if (i < 96 * 32 + 64 * 16) {
        int j = i - 3072;
        int k = j >> 4, o = j & 15;
        k1T[j] = (unsigned short)f2bf(k1[o * 64 + k]);
    }
}

// ---------------- Layer-2 MLP + conv1 via MFMA ------------------------------
// Per wave-group of 16 nodes:
//   GEMM1: H2(16x32) = X(16x96) . W2sT(96x32)   -> 6 mfma_f32_16x16x32_bf16
//   relu + bias, transpose C->A layout via private LDS tile (bf16)
//   GEMM2: Y(16x16)  = [h1|h2](16x64) . k1T(64x16) -> 2 mfma
// Layouts (verified): A[m=lane&15][k=quad*8+j]; B[k=quad*8+j][n=lane&15];
// C/D[row=quad*4+reg][col=lane&15].

__global__ __launch_bounds__(256) void k_mlp_mfma(
    const unsigned short* __restrict__ h1b,
    const unsigned short* __restrict__ hpb, const unsigned short* __restrict__ hnb,
    const unsigned short* __restrict__ W2sT, const unsigned short* __restrict__ k1T,
    const float* __restrict__ b2, const float* __restrict__ bias2,
    const float* __restrict__ bk1,
    float* __restrict__ y1) {
    __shared__ unsigned short h2s[4][16 * 32];     // per-wave transpose tile
    int t = threadIdx.x;
    int wv = t >> 6;
    int lane = t & 63;
    int col = lane & 15;
    int quad = lane >> 4;

    float bv0 = b2[col] + bias2[col];
    float bv1 = b2[col + 16] + bias2[col + 16];
    float bky = bk1[col];

    // B-frags: W2sT (6) + k1T (2), loop-invariant, ~32 VGPR
    bf8 BW[2][3];
#pragma unroll
    for (int nt = 0; nt < 2; nt++)
#pragma unroll
        for (int kt = 0; kt < 3; kt++) {
            bf8 b;
#pragma unroll
            for (int j = 0; j < 8; j++)
                b[j] = (short)W2sT[(kt * 32 + quad * 8 + j) * 32 + nt * 16 + col];
            BW[nt][kt] = b;
        }
    bf8 BK[2];
#pragma unroll
    for (int kt = 0; kt < 2; kt++) {
        bf8 b;
#pragma unroll
        for (int j = 0; j < 8; j++)
            b[j] = (short)k1T[(kt * 32 + quad * 8 + j) * 16 + col];
        BK[kt] = b;
    }
    unsigned short* myT = h2s[wv];

#pragma unroll 1
    for (int g = 0; g < 4; g++) {
        int nbase = blockIdx.x * 256 + wv * 64 + g * 16;
        int node = nbase + col;                     // A-operand row m = col
        // A-frags: all direct bf16 16B loads
        bf8 a0 = *(const bf8*)(h1b + (size_t)node * 32 + quad * 8);
        bf8 a1 = *(const bf8*)(hpb + (size_t)node * 32 + quad * 8);
        bf8 a2 = *(const bf8*)(hnb + (size_t)node * 32 + quad * 8);

        f4 acc0 = {bv0, bv0, bv0, bv0};
        f4 acc1 = {bv1, bv1, bv1, bv1};
        acc0 = __builtin_amdgcn_mfma_f32_16x16x32_bf16(a0, BW[0][0], acc0, 0, 0, 0);
        acc0 = __builtin_amdgcn_mfma_f32_16x16x32_bf16(a1, BW[0][1], acc0, 0, 0, 0);
        acc0 = __builtin_amdgcn_mfma_f32_16x16x32_bf16(a2, BW[0][2], acc0, 0, 0, 0);
        acc1 = __builtin_amdgcn_mfma_f32_16x16x32_bf16(a0, BW[1][0], acc1, 0, 0, 0);
        acc1 = __builtin_amdgcn_mfma_f32_16x16x32_bf16(a1, BW[1][1], acc1, 0, 0, 0);
        acc1 = __builtin_amdgcn_mfma_f32_16x16x32_bf16(a2, BW[1][2], acc1, 0, 0, 0);

        // relu -> bf16 -> LDS (C layout: row=quad*4+i, col)
#pragma unroll
        for (int i = 0; i < 4; i++) {
            int r = quad * 4 + i;
            myT[r * 32 + col]      = (unsigned short)f2bf(fmaxf(acc0[i], 0.f));
            myT[r * 32 + col + 16] = (unsigned short)f2bf(fmaxf(acc1[i], 0.f));
        }
        // read back in A layout (same wave -> compiler inserts lgkm wait)
        bf8 ah2 = *(const bf8*)(myT + col * 32 + quad * 8);

        f4 accy = {bky, bky, bky, bky};
        accy = __builtin_amdgcn_mfma_f32_16x16x32_bf16(a0,  BK[0], accy, 0, 0, 0);
        accy = __builtin_amdgcn_mfma_f32_16x16x32_bf16(ah2, BK[1], accy, 0, 0, 0);
#pragma unroll
        for (int i = 0; i < 4; i++)
            y1[(size_t)(nbase + quad * 4 + i) * 16 + col] = accy[i];
    }
}

// ---------------- Wfc transpose (for coalesced FC reads) ----------------

__global__ void k_transpose(const float* __restrict__ Wfc, float* __restrict__ WfcT) {
    int i = blockIdx.x * 256 + threadIdx.x;
    if (i < 128 * 416) {
        int u = i / 416, c = i - u * 416;
        WfcT[c * 128 + u] = Wfc[i];
    }
}

// ---------------- Head: maxpool -> conv2 -> FC -> classifier -> log_softmax ----

__global__ __launch_bounds__(128) void k_head(
    const float* __restrict__ y1, const float* __restrict__ k2,
    const float* __restrict__ bk2, const float* __restrict__ WfcT,
    const float* __restrict__ bfc, const float* __restrict__ Wc,
    const float* __restrict__ bc, float* __restrict__ out) {
    __shared__ float yl[1296];       // 81 positions x 16 ch, [p][ch]
    __shared__ float zl[16][41];     // after maxpool, [ch][pos<40], pad
    __shared__ float xr[416];        // conv2 out, index oc*13+t
    __shared__ float k2s[1536];
    __shared__ float fl[128];
    __shared__ float ll[10];
    int t = threadIdx.x;
    int b = blockIdx.x;
    const float* yb = y1 + (size_t)b * 1296;
    for (int i = t; i < 1296; i += 128) yl[i] = yb[i];
    for (int i = t; i < 1536; i += 128) k2s[i] = k2[i];
    __syncthreads();
    // maxpool over position pairs (drop pos 80)
    for (int i = t; i < 640; i += 128) {
        int ic = i & 15, p = i >> 4;
        zl[ic][p] = fmaxf(yl[(2 * p) * 16 + ic], yl[(2 * p + 1) * 16 + ic]);
    }
    __syncthreads();
    // conv2: 32 out-ch x 13 positions, stride 3, k=3
    for (int i = t; i < 416; i += 128) {
        int oc = i / 13, tt = i - oc * 13;
        float acc = bk2[oc];
        for (int ic = 0; ic < 16; ic++) {
            const float* kk = &k2s[(oc * 16 + ic) * 3];
            acc += zl[ic][3 * tt]     * kk[0]
                 + zl[ic][3 * tt + 1] * kk[1]
                 + zl[ic][3 * tt + 2] * kk[2];
        }
        xr[i] = acc;
    }
    __syncthreads();
    // FC 416 -> 128, one thread per output, coalesced WfcT reads
    {
        float acc = bfc[t];
        for (int i = 0; i < 416; i++) acc += xr[i] * WfcT[i * 128 + t];
        fl[t] = fmaxf(acc, 0.f);
    }
    __syncthreads();
    if (t < 10) {
        float acc = bc[t];
        for (int u = 0; u < 128; u++) acc += fl[u] * Wc[t * 128 + u];
        ll[t] = acc;
    }
    __syncthreads();
    if (t < 10) {
        float m = -1e30f;
        for (int c = 0; c < 10; c++) m = fmaxf(m, ll[c]);
        float s = 0.f;
        for (int c = 0; c < 10; c++) s += __expf(ll[c] - m);
        out[b * 10 + t] = ll[t] - m - __logf(s);
    }
}

// ---------------- launch ----------------

extern "C" void kernel_launch(void* const* d_in, const int* in_sizes, int n_in,
                              void* d_out, int out_size, void* d_ws, size_t ws_size,
                              hipStream_t stream) {
    const int*   src   = (const int*)d_in[0];
    const int*   dst   = (const int*)d_in[1];
    const float* w     = (const float*)d_in[2];
    const float* W1    = (const float*)d_in[4];
    const float* b1    = (const float*)d_in[5];
    const float* bias1 = (const float*)d_in[6];
    const float* c1s   = (const float*)d_in[7];
    const float* c1p   = (const float*)d_in[8];
    const float* c1n   = (const float*)d_in[9];
    const float* W2    = (const float*)d_in[10];
    const float* b2    = (const float*)d_in[11];
    const float* bias2 = (const float*)d_in[12];
    const float* c2s   = (const float*)d_in[13];
    const float* c2p   = (const float*)d_in[14];
    const float* c2n   = (const float*)d_in[15];
    const float* k1    = (const float*)d_in[16];
    const float* bk1   = (const float*)d_in[17];
    const float* k2    = (const float*)d_in[18];
    const float* bk2   = (const float*)d_in[19];
    const float* Wfc   = (const float*)d_in[20];
    const float* bfc   = (const float*)d_in[21];
    const float* Wc    = (const float*)d_in[22];
    const float* bc    = (const float*)d_in[23];
    const int E = in_sizes[0];
    const int NT = (E + TE - 1) / TE;

    // workspace carve (256B aligned)
    size_t off = 0;
    auto carve = [&](size_t bytes) -> char* {
        char* p = (char*)d_ws + off;
        off = (off + bytes + 255) & ~(size_t)255;
        return p;
    };
    int*   cnt    = (int*)  carve((size_t)NNODES * 4);
    int*   cntp   = (int*)  carve((size_t)NNODES * 4);
    int*   offs   = (int*)  carve((size_t)NNODES * 4);
    int2*  csrB   = (int2*) carve((size_t)E * 8);
    int*   H      = (int*)  carve((size_t)NT * NBUCK * 4);
    int*   T      = (int*)  carve((size_t)NBUCK * 4);
    int*   Bstart = (int*)  carve((size_t)(NBUCK + 1) * 4);
    float* spos   = (float*)carve((size_t)NNODES * 4);
    float* sneg   = (float*)carve((size_t)NNODES * 4);
    unsigned short* h1b = (unsigned short*)carve((size_t)NNODES * 32 * 2);
    unsigned short* hpb = (unsigned short*)carve((size_t)NNODES * 32 * 2);
    unsigned short* hnb = (unsigned short*)carve((size_t)NNODES * 32 * 2);
    float* y1     = (float*)carve((size_t)NNODES * 16 * 4);
    float* WfcT   = (float*)carve((size_t)128 * 416 * 4);
    unsigned short* W2sT = (unsigned short*)carve((size_t)96 * 32 * 2);
    unsigned short* k1T  = (unsigned short*)carve((size_t)64 * 16 * 2);
    (void)ws_size;

    k_hist      <<<NT, 256, 0, stream>>>(dst, H, E);
    k_colscan   <<<NBUCK / 256, 256, 0, stream>>>(H, T, NT);
    k_binscan   <<<1, 256, 0, stream>>>(T, Bstart);
    k_place     <<<NT, 256, 0, stream>>>(src, dst, w, H, Bstart, csrB, E);
    k_sortbucket<<<NBUCK, 256, 0, stream>>>(csrB, Bstart, cnt, cntp, offs);
    k_layer1    <<<NNODES / 8, 256, 0, stream>>>(cnt, cntp, offs, csrB,
                                                 spos, sneg, h1b,
                                                 W1, b1, bias1, c1s, c1p, c1n);
    k_prep      <<<17, 256, 0, stream>>>(W2, c2s, c2p, c2n, k1, W2sT, k1T);
    k_transpose <<<(128 * 416 + 255) / 256, 256, 0, stream>>>(Wfc, WfcT);
    k_agg       <<<NNODES / 8, 256, 0, stream>>>(cnt, cntp, offs, csrB,
                                                 spos, sneg, h1b, hpb, hnb);
    k_mlp_mfma  <<<NNODES / 256, 256, 0, stream>>>(h1b, hpb, hnb, W2sT, k1T,
                                                   b2, bias2, bk1, y1);
    k_head      <<<NGRAPH, 128, 0, stream>>>(y1, k2, bk2, WfcT, bfc, Wc, bc,
                                             (float*)d_out);
}

// Round 14
// 466.062 us; speedup vs baseline: 1.5100x; 1.5100x over previous
//
#include <hip/hip_runtime.h>
#include <hip/hip_bf16.h>

#define NNODES 331776            // 81 * 4096
#define NGRAPH 4096
#define NBUCK  2048              // buckets
#define BNODES 162               // nodes per bucket (2048*162 == 331776)
#define TE     4096              // edges per tile (977 blocks -> ~4/CU)
#define CAP    2560              // max edges/bucket (lambda=1953, 13.7 sigma)
#define CH     64                // tile-chunks for the 3-phase column scan

typedef __attribute__((ext_vector_type(8))) short bf8;   // 8 bf16 (4 VGPR)
typedef __attribute__((ext_vector_type(4))) float f4;    // 4 fp32 acc

static __device__ __forceinline__ short f2bf(float x) {
    return (short)__builtin_bit_cast(unsigned short, __float2bfloat16(x));
}
static __device__ __forceinline__ float bf2f(unsigned short u) {
    return __bfloat162float(__hip_bfloat16_raw{u});
}

// ---------------- deterministic bucket sort (no global atomics) ----------------

__global__ __launch_bounds__(256) void k_hist(const int* __restrict__ dst,
                                              int* __restrict__ H, int E) {
    __shared__ int h[NBUCK];
    int t = threadIdx.x, b = blockIdx.x;
    for (int i = t; i < NBUCK; i += 256) h[i] = 0;
    __syncthreads();
    int lo = b * TE, hi = min(E, lo + TE);
    for (int e = lo + t; e < hi; e += 256)
        atomicAdd(&h[dst[e] / BNODES], 1);
    __syncthreads();
    for (int i = t; i < NBUCK; i += 256) H[b * NBUCK + i] = h[i];
}

// ---- 3-phase per-bin scan across tiles (replaces the 977-deep k_colscan) ----
// Phase A: chunk sums. idx -> (chunk, bin); ~16-deep serial walk.
__global__ __launch_bounds__(256) void k_colA(const int* __restrict__ H,
                                              int* __restrict__ P,
                                              int NT, int CS) {
    int idx = blockIdx.x * 256 + threadIdx.x;       // < CH*NBUCK
    int bin = idx & (NBUCK - 1);
    int chunk = idx >> 11;
    int t0 = chunk * CS, t1 = min(NT, t0 + CS);
    int s = 0;
    for (int t = t0; t < t1; t++) s += H[t * NBUCK + bin];
    P[chunk * NBUCK + bin] = s;
}

// Phase B: exclusive scan of the CH chunk sums per bin; emits T[bin].
__global__ __launch_bounds__(256) void k_colB(int* __restrict__ P,
                                              int* __restrict__ T) {
    int bin = blockIdx.x * 256 + threadIdx.x;       // < NBUCK
    int s = 0;
    for (int c = 0; c < CH; c++) {
        int v = P[c * NBUCK + bin];
        P[c * NBUCK + bin] = s;
        s += v;
    }
    T[bin] = s;
}

// Phase C: in-place exclusive scan within each chunk, offset by chunk base.
__global__ __launch_bounds__(256) void k_colC(int* __restrict__ H,
                                              const int* __restrict__ P,
                                              int NT, int CS) {
    int idx = blockIdx.x * 256 + threadIdx.x;       // < CH*NBUCK
    int bin = idx & (NBUCK - 1);
    int chunk = idx >> 11;
    int t0 = chunk * CS, t1 = min(NT, t0 + CS);
    int s = P[chunk * NBUCK + bin];
    for (int t = t0; t < t1; t++) {
        int v = H[t * NBUCK + bin];
        H[t * NBUCK + bin] = s;
        s += v;
    }
}

// exclusive scan over the 2048 bucket totals -> Bstart[0..NBUCK]
__global__ __launch_bounds__(256) void k_binscan(const int* __restrict__ T,
                                                 int* __restrict__ Bstart) {
    __shared__ int tmp[256];
    int t = threadIdx.x;
    int base = t * 8;
    int loc[8]; int s = 0;
#pragma unroll
    for (int i = 0; i < 8; i++) { loc[i] = s; s += T[base + i]; }
    tmp[t] = s; __syncthreads();
    for (int o = 1; o < 256; o <<= 1) {
        int a = (t >= o) ? tmp[t - o] : 0;
        __syncthreads();
        tmp[t] += a;
        __syncthreads();
    }
    int excl = tmp[t] - s;
#pragma unroll
    for (int i = 0; i < 8; i++) Bstart[base + i] = excl + loc[i];
    if (t == 255) Bstart[NBUCK] = excl + s;
}

// place edges into bucket-major order; payload packs (src | dst_local<<19, esig)
// esig = sign(w)*exp(|w|) computed once here (sign consumed by k_sortbucket).
__global__ __launch_bounds__(256) void k_place(
    const int* __restrict__ src, const int* __restrict__ dst,
    const float* __restrict__ w,
    const int* __restrict__ H, const int* __restrict__ Bstart,
    int2* __restrict__ csrB, int E) {
    __shared__ int cur[NBUCK];
    int t = threadIdx.x, b = blockIdx.x;
    for (int i = t; i < NBUCK; i += 256)
        cur[i] = Bstart[i] + H[b * NBUCK + i];
    __syncthreads();
    int lo = b * TE, hi = min(E, lo + TE);
    for (int e = lo + t; e < hi; e += 256) {
        int d  = dst[e];
        int sx = src[e];
        float wv = w[e];
        float es = 0.f;
        if (wv > 0.f)      es = __expf(wv);
        else if (wv < 0.f) es = -__expf(-wv);
        int bin = d / BNODES;
        int dl  = d - bin * BNODES;
        int p = atomicAdd(&cur[bin], 1);        // LDS atomic; same-bin runs -> consecutive p
        int2 pk;
        pk.x = sx | (dl << 19);
        pk.y = __float_as_int(es);
        csrB[p] = pk;
    }
}

// per-bucket counting sort (in place), key = dst_local*2 + sign:
// each node's edges land [positives | negatives], payload stores |es|.
// Emits cnt[] (total), cntp[] (positive count), offs[] (start).
__global__ __launch_bounds__(256) void k_sortbucket(
    int2* __restrict__ csrB, const int* __restrict__ Bstart,
    int* __restrict__ cnt, int* __restrict__ cntp, int* __restrict__ offs) {
    __shared__ int2 pb[CAP];
    __shared__ int lcnt[BNODES * 2];
    __shared__ int lpos[BNODES * 2];
    int t = threadIdx.x, b = blockIdx.x;
    int lo = Bstart[b];
    int S  = Bstart[b + 1] - lo;
    if (S > CAP) S = CAP;                        // memory-safety guard (never expected)
    for (int i = t; i < BNODES * 2; i += 256) lcnt[i] = 0;
    __syncthreads();
    for (int i = t; i < S; i += 256) {
        int2 pk = csrB[lo + i];                  // coalesced
        pb[i] = pk;
        int key = ((pk.x >> 19) << 1) | ((unsigned)pk.y >> 31);
        atomicAdd(&lcnt[key], 1);
    }
    __syncthreads();
    if (t == 0) {
        int s = 0;
        for (int i = 0; i < BNODES * 2; i++) { lpos[i] = s; s += lcnt[i]; }
    }
    __syncthreads();
    int node0 = b * BNODES;
    for (int i = t; i < BNODES; i += 256) {
        cnt[node0 + i]  = lcnt[2 * i] + lcnt[2 * i + 1];
        cntp[node0 + i] = lcnt[2 * i];
        offs[node0 + i] = lo + lpos[2 * i];
    }
    __syncthreads();
    for (int i = t; i < S; i += 256) {
        int2 pk = pb[i];
        int key = ((pk.x >> 19) << 1) | ((unsigned)pk.y >> 31);
        int p = atomicAdd(&lpos[key], 1);
        int2 outv;
        outv.x = pk.x & 0x7FFFF;                 // unpacked src
        outv.y = pk.y & 0x7FFFFFFF;              // |es| (sign now positional)
        csrB[lo + p] = outv;                     // bucket-local, L2-hot
    }
}

// ---------------- Layer 1 (h0 = deg, 1 feature -> 32), bf16 output ----------
// Magnitude payload; sign from position (j+f < np).

__global__ __launch_bounds__(256) void k_layer1(
    const int* __restrict__ cnt, const int* __restrict__ cntp,
    const int* __restrict__ offs, const int2* __restrict__ csr,
    float* __restrict__ spos, float* __restrict__ sneg,
    unsigned short* __restrict__ h1b,
    const float* __restrict__ W1, const float* __restrict__ b1,
    const float* __restrict__ bias1,
    const float* __restrict__ c1s, const float* __restrict__ c1p,
    const float* __restrict__ c1n) {
    int t = threadIdx.x;
    int g = t >> 5, f = t & 31;
    int d = blockIdx.x * 8 + g;
    int beg = offs[d];
    int len = cnt[d];
    int np  = cntp[d];
    float sp = 0.f, sn = 0.f, up = 0.f, un = 0.f;
    for (int j = 0; j < len; j += 32) {
        int rem = len - j;
        if (f < rem) {
            int2 sw = csr[beg + j + f];            // coalesced 8B/lane
            float es = __int_as_float(sw.y);        // |es|
            float degs = (float)cnt[sw.x];          // parallel gather, L2-hot
            float ep = (j + f < np) ? es : 0.f;
            float en = es - ep;
            sp += ep; sn += en;
            up = fmaf(degs, ep, up); un = fmaf(degs, en, un);
        }
    }
    for (int m = 16; m; m >>= 1) {
        sp += __shfl_xor(sp, m, 32);
        sn += __shfl_xor(sn, m, 32);
        up += __shfl_xor(up, m, 32);
        un += __shfl_xor(un, m, 32);
    }
    if (f == 0) { spos[d] = sp; sneg[d] = sn; }
    float hp = up / fmaxf(sp, 1e-20f);
    float hn = un / fmaxf(sn, 1e-20f);
    float x0 = c1s[0] * (float)len;   // deg[d] == len
    float x1 = c1p[0] * hp;
    float x2 = c1n[0] * hn;
    float v = W1[f * 3] * x0 + W1[f * 3 + 1] * x1 + W1[f * 3 + 2] * x2
            + b1[f] + bias1[f];
    v = fmaxf(v, 0.f);
    h1b[d * 32 + f] = (unsigned short)f2bf(v);      // bf16 table (gathered + MFMA A)
}

// ---------------- Layer-2 aggregation ----------------------------------------
// Half-wave per node; sign-partitioned ranges: 2 shuffles + 1 fma + 1 cvt per
// edge, zero sign logic (pads get e=0 via the range guard; sx=0 pads hit the
// L1-hot node-0 line). 8-deep gather batches keep loads in flight.

static __device__ __forceinline__ float range_accum(
    const int2* __restrict__ csr, const unsigned short* __restrict__ h1b,
    int rbeg, int count, int f) {
    float a = 0.f;
    for (int j = 0; j < count; j += 32) {
        int rem = count - j;
        int sx = 0;
        float e = 0.f;
        if (f < rem) {
            int2 pk = csr[rbeg + j + f];           // coalesced 8B/lane
            sx = pk.x;
            e = __int_as_float(pk.y);              // |es|
        }
        int n = rem < 32 ? rem : 32;
        for (int q = 0; q < n; q += 8) {
            float ev[8], hv[8];
#pragma unroll
            for (int u = 0; u < 8; u++) {
                int s = __shfl(sx, q + u, 32);
                ev[u] = __shfl(e, q + u, 32);
                hv[u] = bf2f(h1b[s * 32 + f]);     // 8 independent gathers
            }
#pragma unroll
            for (int u = 0; u < 8; u++) a = fmaf(ev[u], hv[u], a);
        }
    }
    return a;
}

__global__ __launch_bounds__(256) void k_agg(
    const int* __restrict__ cnt, const int* __restrict__ cntp,
    const int* __restrict__ offs, const int2* __restrict__ csr,
    const float* __restrict__ spos, const float* __restrict__ sneg,
    const unsigned short* __restrict__ h1b,
    unsigned short* __restrict__ hpb, unsigned short* __restrict__ hnb) {
    int t = threadIdx.x;
    int g = t >> 5, f = t & 31;
    int d = blockIdx.x * 8 + g;     // NNODES % 8 == 0
    int beg = offs[d];
    int len = cnt[d];
    int np  = cntp[d];
    float ap = range_accum(csr, h1b, beg, np, f);
    float an = range_accum(csr, h1b, beg + np, len - np, f);
    hpb[d * 32 + f] = (unsigned short)f2bf(ap / fmaxf(spos[d], 1e-20f));
    hnb[d * 32 + f] = (unsigned short)f2bf(an / fmaxf(sneg[d], 1e-20f));
}

// ---------------- weight prep: bf16 transposed, scales folded ---------------
// W2sT[k][n] = bf16(W2[n][k] * c_{k/32})   (96 x 32)
// k1T[k][o]  = bf16(k1[o][k])              (64 x 16)

__global__ __launch_bounds__(256) void k_prep(
    const float* __restrict__ W2, const float* __restrict__ c2s,
    const float* __restrict__ c2p, const float* __restrict__ c2n,
    const float* __restrict__ k1,
    unsigned short* __restrict__ W2sT, unsigned short* __restrict__ k1T) {
    int i = blockIdx.x * 256 + threadIdx.x;
    if (i < 96 * 32) {
        int k = i >> 5, n = i & 31;
        float sc = (k < 32) ? c2s[0] : ((k < 64) ? c2p[0] : c2n[0]);
        W2sT[i] = (unsigned short)f2bf(W2[n * 96 + k] * sc);
    } else if (i < 96 * 32 + 64 * 16) {
        int j = i - 3072;
        int k = j >> 4, o = j & 15;
        k1T[j] = (unsigned short)f2bf(k1[o * 64 + k]);
    }
}

// ---------------- Layer-2 MLP + conv1 via MFMA ------------------------------
// Per wave-group of 16 nodes:
//   GEMM1: H2(16x32) = X(16x96) . W2sT(96x32)   -> 6 mfma_f32_16x16x32_bf16
//   relu + bias, transpose C->A layout via private LDS tile (bf16)
//   GEMM2: Y(16x16)  = [h1|h2](16x64) . k1T(64x16) -> 2 mfma
// Layouts (verified): A[m=lane&15][k=quad*8+j]; B[k=quad*8+j][n=lane&15];
// C/D[row=quad*4+reg][col=lane&15].

__global__ __launch_bounds__(256) void k_mlp_mfma(
    const unsigned short* __restrict__ h1b,
    const unsigned short* __restrict__ hpb, const unsigned short* __restrict__ hnb,
    const unsigned short* __restrict__ W2sT, const unsigned short* __restrict__ k1T,
    const float* __restrict__ b2, const float* __restrict__ bias2,
    const float* __restrict__ bk1,
    float* __restrict__ y1) {
    __shared__ unsigned short h2s[4][16 * 32];     // per-wave transpose tile
    int t = threadIdx.x;
    int wv = t >> 6;
    int lane = t & 63;
    int col = lane & 15;
    int quad = lane >> 4;

    float bv0 = b2[col] + bias2[col];
    float bv1 = b2[col + 16] + bias2[col + 16];
    float bky = bk1[col];

    // B-frags: W2sT (6) + k1T (2), loop-invariant, ~32 VGPR
    bf8 BW[2][3];
#pragma unroll
    for (int nt = 0; nt < 2; nt++)
#pragma unroll
        for (int kt = 0; kt < 3; kt++) {
            bf8 b;
#pragma unroll
            for (int j = 0; j < 8; j++)
                b[j] = (short)W2sT[(kt * 32 + quad * 8 + j) * 32 + nt * 16 + col];
            BW[nt][kt] = b;
        }
    bf8 BK[2];
#pragma unroll
    for (int kt = 0; kt < 2; kt++) {
        bf8 b;
#pragma unroll
        for (int j = 0; j < 8; j++)
            b[j] = (short)k1T[(kt * 32 + quad * 8 + j) * 16 + col];
        BK[kt] = b;
    }
    unsigned short* myT = h2s[wv];

#pragma unroll 1
    for (int g = 0; g < 4; g++) {
        int nbase = blockIdx.x * 256 + wv * 64 + g * 16;
        int node = nbase + col;                     // A-operand row m = col
        // A-frags: all direct bf16 16B loads
        bf8 a0 = *(const bf8*)(h1b + (size_t)node * 32 + quad * 8);
        bf8 a1 = *(const bf8*)(hpb + (size_t)node * 32 + quad * 8);
        bf8 a2 = *(const bf8*)(hnb + (size_t)node * 32 + quad * 8);

        f4 acc0 = {bv0, bv0, bv0, bv0};
        f4 acc1 = {bv1, bv1, bv1, bv1};
        acc0 = __builtin_amdgcn_mfma_f32_16x16x32_bf16(a0, BW[0][0], acc0, 0, 0, 0);
        acc0 = __builtin_amdgcn_mfma_f32_16x16x32_bf16(a1, BW[0][1], acc0, 0, 0, 0);
        acc0 = __builtin_amdgcn_mfma_f32_16x16x32_bf16(a2, BW[0][2], acc0, 0, 0, 0);
        acc1 = __builtin_amdgcn_mfma_f32_16x16x32_bf16(a0, BW[1][0], acc1, 0, 0, 0);
        acc1 = __builtin_amdgcn_mfma_f32_16x16x32_bf16(a1, BW[1][1], acc1, 0, 0, 0);
        acc1 = __builtin_amdgcn_mfma_f32_16x16x32_bf16(a2, BW[1][2], acc1, 0, 0, 0);

        // relu -> bf16 -> LDS (C layout: row=quad*4+i, col)
#pragma unroll
        for (int i = 0; i < 4; i++) {
            int r = quad * 4 + i;
            myT[r * 32 + col]      = (unsigned short)f2bf(fmaxf(acc0[i], 0.f));
            myT[r * 32 + col + 16] = (unsigned short)f2bf(fmaxf(acc1[i], 0.f));
        }
        // read back in A layout (same wave -> compiler inserts lgkm wait)
        bf8 ah2 = *(const bf8*)(myT + col * 32 + quad * 8);

        f4 accy = {bky, bky, bky, bky};
        accy = __builtin_amdgcn_mfma_f32_16x16x32_bf16(a0,  BK[0], accy, 0, 0, 0);
        accy = __builtin_amdgcn_mfma_f32_16x16x32_bf16(ah2, BK[1], accy, 0, 0, 0);
#pragma unroll
        for (int i = 0; i < 4; i++)
            y1[(size_t)(nbase + quad * 4 + i) * 16 + col] = accy[i];
    }
}

// ---------------- Wfc transpose (for coalesced FC reads) ----------------

__global__ void k_transpose(const float* __restrict__ Wfc, float* __restrict__ WfcT) {
    int i = blockIdx.x * 256 + threadIdx.x;
    if (i < 128 * 416) {
        int u = i / 416, c = i - u * 416;
        WfcT[c * 128 + u] = Wfc[i];
    }
}

// ---------------- Head: maxpool -> conv2 -> FC -> classifier -> log_softmax ----

__global__ __launch_bounds__(128) void k_head(
    const float* __restrict__ y1, const float* __restrict__ k2,
    const float* __restrict__ bk2, const float* __restrict__ WfcT,
    const float* __restrict__ bfc, const float* __restrict__ Wc,
    const float* __restrict__ bc, float* __restrict__ out) {
    __shared__ float yl[1296];       // 81 positions x 16 ch, [p][ch]
    __shared__ float zl[16][41];     // after maxpool, [ch][pos<40], pad
    __shared__ float xr[416];        // conv2 out, index oc*13+t
    __shared__ float k2s[1536];
    __shared__ float fl[128];
    __shared__ float ll[10];
    int t = threadIdx.x;
    int b = blockIdx.x;
    const float* yb = y1 + (size_t)b * 1296;
    for (int i = t; i < 1296; i += 128) yl[i] = yb[i];
    for (int i = t; i < 1536; i += 128) k2s[i] = k2[i];
    __syncthreads();
    // maxpool over position pairs (drop pos 80)
    for (int i = t; i < 640; i += 128) {
        int ic = i & 15, p = i >> 4;
        zl[ic][p] = fmaxf(yl[(2 * p) * 16 + ic], yl[(2 * p + 1) * 16 + ic]);
    }
    __syncthreads();
    // conv2: 32 out-ch x 13 positions, stride 3, k=3
    for (int i = t; i < 416; i += 128) {
        int oc = i / 13, tt = i - oc * 13;
        float acc = bk2[oc];
        for (int ic = 0; ic < 16; ic++) {
            const float* kk = &k2s[(oc * 16 + ic) * 3];
            acc += zl[ic][3 * tt]     * kk[0]
                 + zl[ic][3 * tt + 1] * kk[1]
                 + zl[ic][3 * tt + 2] * kk[2];
        }
        xr[i] = acc;
    }
    __syncthreads();
    // FC 416 -> 128, one thread per output, coalesced WfcT reads
    {
        float acc = bfc[t];
        for (int i = 0; i < 416; i++) acc += xr[i] * WfcT[i * 128 + t];
        fl[t] = fmaxf(acc, 0.f);
    }
    __syncthreads();
    if (t < 10) {
        float acc = bc[t];
        for (int u = 0; u < 128; u++) acc += fl[u] * Wc[t * 128 + u];
        ll[t] = acc;
    }
    __syncthreads();
    if (t < 10) {
        float m = -1e30f;
        for (int c = 0; c < 10; c++) m = fmaxf(m, ll[c]);
        float s = 0.f;
        for (int c = 0; c < 10; c++) s += __expf(ll[c] - m);
        out[b * 10 + t] = ll[t] - m - __logf(s);
    }
}

// ---------------- launch ----------------

extern "C" void kernel_launch(void* const* d_in, const int* in_sizes, int n_in,
                              void* d_out, int out_size, void* d_ws, size_t ws_size,
                              hipStream_t stream) {
    const int*   src   = (const int*)d_in[0];
    const int*   dst   = (const int*)d_in[1];
    const float* w     = (const float*)d_in[2];
    const float* W1    = (const float*)d_in[4];
    const float* b1    = (const float*)d_in[5];
    const float* bias1 = (const float*)d_in[6];
    const float* c1s   = (const float*)d_in[7];
    const float* c1p   = (const float*)d_in[8];
    const float* c1n   = (const float*)d_in[9];
    const float* W2    = (const float*)d_in[10];
    const float* b2    = (const float*)d_in[11];
    const float* bias2 = (const float*)d_in[12];
    const float* c2s   = (const float*)d_in[13];
    const float* c2p   = (const float*)d_in[14];
    const float* c2n   = (const float*)d_in[15];
    const float* k1    = (const float*)d_in[16];
    const float* bk1   = (const float*)d_in[17];
    const float* k2    = (const float*)d_in[18];
    const float* bk2   = (const float*)d_in[19];
    const float* Wfc   = (const float*)d_in[20];
    const float* bfc   = (const float*)d_in[21];
    const float* Wc    = (const float*)d_in[22];
    const float* bc    = (const float*)d_in[23];
    const int E = in_sizes[0];
    const int NT = (E + TE - 1) / TE;
    const int CS = (NT + CH - 1) / CH;

    // workspace carve (256B aligned)
    size_t off = 0;
    auto carve = [&](size_t bytes) -> char* {
        char* p = (char*)d_ws + off;
        off = (off + bytes + 255) & ~(size_t)255;
        return p;
    };
    int*   cnt    = (int*)  carve((size_t)NNODES * 4);
    int*   cntp   = (int*)  carve((size_t)NNODES * 4);
    int*   offs   = (int*)  carve((size_t)NNODES * 4);
    int2*  csrB   = (int2*) carve((size_t)E * 8);
    int*   H      = (int*)  carve((size_t)NT * NBUCK * 4);
    int*   P      = (int*)  carve((size_t)CH * NBUCK * 4);
    int*   T      = (int*)  carve((size_t)NBUCK * 4);
    int*   Bstart = (int*)  carve((size_t)(NBUCK + 1) * 4);
    float* spos   = (float*)carve((size_t)NNODES * 4);
    float* sneg   = (float*)carve((size_t)NNODES * 4);
    unsigned short* h1b = (unsigned short*)carve((size_t)NNODES * 32 * 2);
    unsigned short* hpb = (unsigned short*)carve((size_t)NNODES * 32 * 2);
    unsigned short* hnb = (unsigned short*)carve((size_t)NNODES * 32 * 2);
    float* y1     = (float*)carve((size_t)NNODES * 16 * 4);
    float* WfcT   = (float*)carve((size_t)128 * 416 * 4);
    unsigned short* W2sT = (unsigned short*)carve((size_t)96 * 32 * 2);
    unsigned short* k1T  = (unsigned short*)carve((size_t)64 * 16 * 2);
    (void)ws_size;

    k_hist      <<<NT, 256, 0, stream>>>(dst, H, E);
    k_colA      <<<CH * NBUCK / 256, 256, 0, stream>>>(H, P, NT, CS);
    k_colB      <<<NBUCK / 256, 256, 0, stream>>>(P, T);
    k_colC      <<<CH * NBUCK / 256, 256, 0, stream>>>(H, P, NT, CS);
    k_binscan   <<<1, 256, 0, stream>>>(T, Bstart);
    k_place     <<<NT, 256, 0, stream>>>(src, dst, w, H, Bstart, csrB, E);
    k_sortbucket<<<NBUCK, 256, 0, stream>>>(csrB, Bstart, cnt, cntp, offs);
    k_layer1    <<<NNODES / 8, 256, 0, stream>>>(cnt, cntp, offs, csrB,
                                                 spos, sneg, h1b,
                                                 W1, b1, bias1, c1s, c1p, c1n);
    k_prep      <<<17, 256, 0, stream>>>(W2, c2s, c2p, c2n, k1, W2sT, k1T);
    k_transpose <<<(128 * 416 + 255) / 256, 256, 0, stream>>>(Wfc, WfcT);
    k_agg       <<<NNODES / 8, 256, 0, stream>>>(cnt, cntp, offs, csrB,
                                                 spos, sneg, h1b, hpb, hnb);
    k_mlp_mfma  <<<NNODES / 256, 256, 0, stream>>>(h1b, hpb, hnb, W2sT, k1T,
                                                   b2, bias2, bk1, y1);
    k_head      <<<NGRAPH, 128, 0, stream>>>(y1, k2, bk2, WfcT, bfc, Wc, bc,
                                             (float*)d_out);
}

// Round 15
// 437.953 us; speedup vs baseline: 1.6070x; 1.0642x over previous
//
#include <hip/hip_runtime.h>
#include <hip/hip_bf16.h>

#define NNODES 331776            // 81 * 4096
#define NGRAPH 4096
#define NBUCK  2048              // buckets
#define BNODES 162               // nodes per bucket (2048*162 == 331776)
#define TE     4096              // edges per tile (977 blocks -> ~4/CU)
#define CAP    2560              // max edges/bucket (lambda=1953, 13.7 sigma)
#define CH     64                // tile-chunks for the 3-phase column scan
#define EB     16                // edges per thread in hist/place (TE/256)

typedef __attribute__((ext_vector_type(8))) short bf8;   // 8 bf16 (4 VGPR)
typedef __attribute__((ext_vector_type(4))) float f4;    // 4 fp32 acc

static __device__ __forceinline__ short f2bf(float x) {
    return (short)__builtin_bit_cast(unsigned short, __float2bfloat16(x));
}
static __device__ __forceinline__ float bf2f(unsigned short u) {
    return __bfloat162float(__hip_bfloat16_raw{u});
}

// ---------------- deterministic bucket sort (no global atomics) ----------------
// 16-edge explicit batching: VGPR_Count=12 left zero ILP (R14: 97us, VALU 2.5%).

__global__ __launch_bounds__(256) void k_hist(const int* __restrict__ dst,
                                              int* __restrict__ H, int E) {
    __shared__ int h[NBUCK];
    int t = threadIdx.x, b = blockIdx.x;
    for (int i = t; i < NBUCK; i += 256) h[i] = 0;
    __syncthreads();
    int lo = b * TE;
    int bins[EB]; bool ok[EB];
#pragma unroll
    for (int i = 0; i < EB; i++) {
        int e = lo + i * 256 + t;
        ok[i] = e < E;
        bins[i] = ok[i] ? (dst[e] / BNODES) : 0;
    }
#pragma unroll
    for (int i = 0; i < EB; i++)
        if (ok[i]) atomicAdd(&h[bins[i]], 1);
    __syncthreads();
    for (int i = t; i < NBUCK; i += 256) H[b * NBUCK + i] = h[i];
}

// ---- 3-phase per-bin scan across tiles ----
__global__ __launch_bounds__(256) void k_colA(const int* __restrict__ H,
                                              int* __restrict__ P,
                                              int NT, int CS) {
    int idx = blockIdx.x * 256 + threadIdx.x;       // < CH*NBUCK
    int bin = idx & (NBUCK - 1);
    int chunk = idx >> 11;
    int t0 = chunk * CS, t1 = min(NT, t0 + CS);
    int s = 0;
    for (int t = t0; t < t1; t++) s += H[t * NBUCK + bin];
    P[chunk * NBUCK + bin] = s;
}

__global__ __launch_bounds__(256) void k_colB(int* __restrict__ P,
                                              int* __restrict__ T) {
    int bin = blockIdx.x * 256 + threadIdx.x;       // < NBUCK
    int s = 0;
    for (int c = 0; c < CH; c++) {
        int v = P[c * NBUCK + bin];
        P[c * NBUCK + bin] = s;
        s += v;
    }
    T[bin] = s;
}

__global__ __launch_bounds__(256) void k_colC(int* __restrict__ H,
                                              const int* __restrict__ P,
                                              int NT, int CS) {
    int idx = blockIdx.x * 256 + threadIdx.x;       // < CH*NBUCK
    int bin = idx & (NBUCK - 1);
    int chunk = idx >> 11;
    int t0 = chunk * CS, t1 = min(NT, t0 + CS);
    int s = P[chunk * NBUCK + bin];
    for (int t = t0; t < t1; t++) {
        int v = H[t * NBUCK + bin];
        H[t * NBUCK + bin] = s;
        s += v;
    }
}

// exclusive scan over the 2048 bucket totals -> Bstart[0..NBUCK]
__global__ __launch_bounds__(256) void k_binscan(const int* __restrict__ T,
                                                 int* __restrict__ Bstart) {
    __shared__ int tmp[256];
    int t = threadIdx.x;
    int base = t * 8;
    int loc[8]; int s = 0;
#pragma unroll
    for (int i = 0; i < 8; i++) { loc[i] = s; s += T[base + i]; }
    tmp[t] = s; __syncthreads();
    for (int o = 1; o < 256; o <<= 1) {
        int a = (t >= o) ? tmp[t - o] : 0;
        __syncthreads();
        tmp[t] += a;
        __syncthreads();
    }
    int excl = tmp[t] - s;
#pragma unroll
    for (int i = 0; i < 8; i++) Bstart[base + i] = excl + loc[i];
    if (t == 255) Bstart[NBUCK] = excl + s;
}

// place edges into bucket-major order; payload packs (src | dst_local<<19, esig).
// 16-edge phase-split batching: 16 loads -> 16 expf -> 16 LDS atomics -> 16
// scatter stores, all independent -> ~16 round-trips in flight per thread.
__global__ __launch_bounds__(256) void k_place(
    const int* __restrict__ src, const int* __restrict__ dst,
    const float* __restrict__ w,
    const int* __restrict__ H, const int* __restrict__ Bstart,
    int2* __restrict__ csrB, int E) {
    __shared__ int cur[NBUCK];
    int t = threadIdx.x, b = blockIdx.x;
    for (int i = t; i < NBUCK; i += 256)
        cur[i] = Bstart[i] + H[b * NBUCK + i];
    __syncthreads();
    int lo = b * TE;
    int dd[EB], sx[EB]; float wv[EB]; bool ok[EB];
#pragma unroll
    for (int i = 0; i < EB; i++) {
        int e = lo + i * 256 + t;
        ok[i] = e < E;
        if (ok[i]) { dd[i] = dst[e]; sx[i] = src[e]; wv[i] = w[e]; }
    }
    int pk0[EB]; float es[EB]; int bin[EB];
#pragma unroll
    for (int i = 0; i < EB; i++) {
        if (ok[i]) {
            float v = wv[i];
            float e2 = 0.f;
            if (v > 0.f)      e2 = __expf(v);
            else if (v < 0.f) e2 = -__expf(-v);
            es[i] = e2;
            bin[i] = dd[i] / BNODES;
            pk0[i] = sx[i] | ((dd[i] - bin[i] * BNODES) << 19);
        }
    }
    int p[EB];
#pragma unroll
    for (int i = 0; i < EB; i++)
        if (ok[i]) p[i] = atomicAdd(&cur[bin[i]], 1);
#pragma unroll
    for (int i = 0; i < EB; i++)
        if (ok[i]) {
            int2 pk;
            pk.x = pk0[i];
            pk.y = __float_as_int(es[i]);
            csrB[p[i]] = pk;
        }
}

// per-bucket counting sort (in place), key = dst_local*2 + sign:
// each node's edges land [positives | negatives], payload stores |es|.
__global__ __launch_bounds__(256) void k_sortbucket(
    int2* __restrict__ csrB, const int* __restrict__ Bstart,
    int* __restrict__ cnt, int* __restrict__ cntp, int* __restrict__ offs) {
    __shared__ int2 pb[CAP];
    __shared__ int lcnt[BNODES * 2];
    __shared__ int lpos[BNODES * 2];
    int t = threadIdx.x, b = blockIdx.x;
    int lo = Bstart[b];
    int S  = Bstart[b + 1] - lo;
    if (S > CAP) S = CAP;                        // memory-safety guard (never expected)
    for (int i = t; i < BNODES * 2; i += 256) lcnt[i] = 0;
    __syncthreads();
    for (int i = t; i < S; i += 256) {
        int2 pk = csrB[lo + i];                  // coalesced
        pb[i] = pk;
        int key = ((pk.x >> 19) << 1) | ((unsigned)pk.y >> 31);
        atomicAdd(&lcnt[key], 1);
    }
    __syncthreads();
    if (t == 0) {
        int s = 0;
        for (int i = 0; i < BNODES * 2; i++) { lpos[i] = s; s += lcnt[i]; }
    }
    __syncthreads();
    int node0 = b * BNODES;
    for (int i = t; i < BNODES; i += 256) {
        cnt[node0 + i]  = lcnt[2 * i] + lcnt[2 * i + 1];
        cntp[node0 + i] = lcnt[2 * i];
        offs[node0 + i] = lo + lpos[2 * i];
    }
    __syncthreads();
    for (int i = t; i < S; i += 256) {
        int2 pk = pb[i];
        int key = ((pk.x >> 19) << 1) | ((unsigned)pk.y >> 31);
        int p = atomicAdd(&lpos[key], 1);
        int2 outv;
        outv.x = pk.x & 0x7FFFF;                 // unpacked src
        outv.y = pk.y & 0x7FFFFFFF;              // |es| (sign now positional)
        csrB[lo + p] = outv;                     // bucket-local, L2-hot
    }
}

// ---------------- Layer 1 (h0 = deg, 1 feature -> 32), bf16 output ----------

__global__ __launch_bounds__(256) void k_layer1(
    const int* __restrict__ cnt, const int* __restrict__ cntp,
    const int* __restrict__ offs, const int2* __restrict__ csr,
    float* __restrict__ spos, float* __restrict__ sneg,
    unsigned short* __restrict__ h1b,
    const float* __restrict__ W1, const float* __restrict__ b1,
    const float* __restrict__ bias1,
    const float* __restrict__ c1s, const float* __restrict__ c1p,
    const float* __restrict__ c1n) {
    int t = threadIdx.x;
    int g = t >> 5, f = t & 31;
    int d = blockIdx.x * 8 + g;
    int beg = offs[d];
    int len = cnt[d];
    int np  = cntp[d];
    float sp = 0.f, sn = 0.f, up = 0.f, un = 0.f;
    for (int j = 0; j < len; j += 32) {
        int rem = len - j;
        if (f < rem) {
            int2 sw = csr[beg + j + f];            // coalesced 8B/lane
            float es = __int_as_float(sw.y);        // |es|
            float degs = (float)cnt[sw.x];          // parallel gather, L2-hot
            float ep = (j + f < np) ? es : 0.f;
            float en = es - ep;
            sp += ep; sn += en;
            up = fmaf(degs, ep, up); un = fmaf(degs, en, un);
        }
    }
    for (int m = 16; m; m >>= 1) {
        sp += __shfl_xor(sp, m, 32);
        sn += __shfl_xor(sn, m, 32);
        up += __shfl_xor(up, m, 32);
        un += __shfl_xor(un, m, 32);
    }
    if (f == 0) { spos[d] = sp; sneg[d] = sn; }
    float hp = up / fmaxf(sp, 1e-20f);
    float hn = un / fmaxf(sn, 1e-20f);
    float x0 = c1s[0] * (float)len;   // deg[d] == len
    float x1 = c1p[0] * hp;
    float x2 = c1n[0] * hn;
    float v = W1[f * 3] * x0 + W1[f * 3 + 1] * x1 + W1[f * 3 + 2] * x2
            + b1[f] + bias1[f];
    v = fmaxf(v, 0.f);
    h1b[d * 32 + f] = (unsigned short)f2bf(v);      // bf16 table (gathered + MFMA A)
}

// ---------------- Layer-2 aggregation ----------------------------------------

static __device__ __forceinline__ float range_accum(
    const int2* __restrict__ csr, const unsigned short* __restrict__ h1b,
    int rbeg, int count, int f) {
    float a = 0.f;
    for (int j = 0; j < count; j += 32) {
        int rem = count - j;
        int sx = 0;
        float e = 0.f;
        if (f < rem) {
            int2 pk = csr[rbeg + j + f];           // coalesced 8B/lane
            sx = pk.x;
            e = __int_as_float(pk.y);              // |es|
        }
        int n = rem < 32 ? rem : 32;
        for (int q = 0; q < n; q += 8) {
            float ev[8], hv[8];
#pragma unroll
            for (int u = 0; u < 8; u++) {
                int s = __shfl(sx, q + u, 32);
                ev[u] = __shfl(e, q + u, 32);
                hv[u] = bf2f(h1b[s * 32 + f]);     // 8 independent gathers
            }
#pragma unroll
            for (int u = 0; u < 8; u++) a = fmaf(ev[u], hv[u], a);
        }
    }
    return a;
}

__global__ __launch_bounds__(256) void k_agg(
    const int* __restrict__ cnt, const int* __restrict__ cntp,
    const int* __restrict__ offs, const int2* __restrict__ csr,
    const float* __restrict__ spos, const float* __restrict__ sneg,
    const unsigned short* __restrict__ h1b,
    unsigned short* __restrict__ hpb, unsigned short* __restrict__ hnb) {
    int t = threadIdx.x;
    int g = t >> 5, f = t & 31;
    int d = blockIdx.x * 8 + g;     // NNODES % 8 == 0
    int beg = offs[d];
    int len = cnt[d];
    int np  = cntp[d];
    float ap = range_accum(csr, h1b, beg, np, f);
    float an = range_accum(csr, h1b, beg + np, len - np, f);
    hpb[d * 32 + f] = (unsigned short)f2bf(ap / fmaxf(spos[d], 1e-20f));
    hnb[d * 32 + f] = (unsigned short)f2bf(an / fmaxf(sneg[d], 1e-20f));
}

// ---------------- weight prep: bf16 transposed, scales folded ---------------

__global__ __launch_bounds__(256) void k_prep(
    const float* __restrict__ W2, const float* __restrict__ c2s,
    const float* __restrict__ c2p, const float* __restrict__ c2n,
    const float* __restrict__ k1,
    unsigned short* __restrict__ W2sT, unsigned short* __restrict__ k1T) {
    int i = blockIdx.x * 256 + threadIdx.x;
    if (i < 96 * 32) {
        int k = i >> 5, n = i & 31;
        float sc = (k < 32) ? c2s[0] : ((k < 64) ? c2p[0] : c2n[0]);
        W2sT[i] = (unsigned short)f2bf(W2[n * 96 + k] * sc);
    } else if (i < 96 * 32 + 64 * 16) {
        int j = i - 3072;
        int k = j >> 4, o = j & 15;
        k1T[j] = (unsigned short)f2bf(k1[o * 64 + k]);
    }
}

// ---------------- Layer-2 MLP + conv1 via MFMA ------------------------------

__global__ __launch_bounds__(256) void k_mlp_mfma(
    const unsigned short* __restrict__ h1b,
    const unsigned short* __restrict__ hpb, const unsigned short* __restrict__ hnb,
    const unsigned short* __restrict__ W2sT, const unsigned short* __restrict__ k1T,
    const float* __restrict__ b2, const float* __restrict__ bias2,
    const float* __restrict__ bk1,
    float* __restrict__ y1) {
    __shared__ unsigned short h2s[4][16 * 32];     // per-wave transpose tile
    int t = threadIdx.x;
    int wv = t >> 6;
    int lane = t & 63;
    int col = lane & 15;
    int quad = lane >> 4;

    float bv0 = b2[col] + bias2[col];
    float bv1 = b2[col + 16] + bias2[col + 16];
    float bky = bk1[col];

    bf8 BW[2][3];
#pragma unroll
    for (int nt = 0; nt < 2; nt++)
#pragma unroll
        for (int kt = 0; kt < 3; kt++) {
            bf8 b;
#pragma unroll
            for (int j = 0; j < 8; j++)
                b[j] = (short)W2sT[(kt * 32 + quad * 8 + j) * 32 + nt * 16 + col];
            BW[nt][kt] = b;
        }
    bf8 BK[2];
#pragma unroll
    for (int kt = 0; kt < 2; kt++) {
        bf8 b;
#pragma unroll
        for (int j = 0; j < 8; j++)
            b[j] = (short)k1T[(kt * 32 + quad * 8 + j) * 16 + col];
        BK[kt] = b;
    }
    unsigned short* myT = h2s[wv];

#pragma unroll 1
    for (int g = 0; g < 4; g++) {
        int nbase = blockIdx.x * 256 + wv * 64 + g * 16;
        int node = nbase + col;                     // A-operand row m = col
        bf8 a0 = *(const bf8*)(h1b + (size_t)node * 32 + quad * 8);
        bf8 a1 = *(const bf8*)(hpb + (size_t)node * 32 + quad * 8);
        bf8 a2 = *(const bf8*)(hnb + (size_t)node * 32 + quad * 8);

        f4 acc0 = {bv0, bv0, bv0, bv0};
        f4 acc1 = {bv1, bv1, bv1, bv1};
        acc0 = __builtin_amdgcn_mfma_f32_16x16x32_bf16(a0, BW[0][0], acc0, 0, 0, 0);
        acc0 = __builtin_amdgcn_mfma_f32_16x16x32_bf16(a1, BW[0][1], acc0, 0, 0, 0);
        acc0 = __builtin_amdgcn_mfma_f32_16x16x32_bf16(a2, BW[0][2], acc0, 0, 0, 0);
        acc1 = __builtin_amdgcn_mfma_f32_16x16x32_bf16(a0, BW[1][0], acc1, 0, 0, 0);
        acc1 = __builtin_amdgcn_mfma_f32_16x16x32_bf16(a1, BW[1][1], acc1, 0, 0, 0);
        acc1 = __builtin_amdgcn_mfma_f32_16x16x32_bf16(a2, BW[1][2], acc1, 0, 0, 0);

#pragma unroll
        for (int i = 0; i < 4; i++) {
            int r = quad * 4 + i;
            myT[r * 32 + col]      = (unsigned short)f2bf(fmaxf(acc0[i], 0.f));
            myT[r * 32 + col + 16] = (unsigned short)f2bf(fmaxf(acc1[i], 0.f));
        }
        bf8 ah2 = *(const bf8*)(myT + col * 32 + quad * 8);

        f4 accy = {bky, bky, bky, bky};
        accy = __builtin_amdgcn_mfma_f32_16x16x32_bf16(a0,  BK[0], accy, 0, 0, 0);
        accy = __builtin_amdgcn_mfma_f32_16x16x32_bf16(ah2, BK[1], accy, 0, 0, 0);
#pragma unroll
        for (int i = 0; i < 4; i++)
            y1[(size_t)(nbase + quad * 4 + i) * 16 + col] = accy[i];
    }
}

// ---------------- Wfc transpose (for coalesced FC reads) ----------------

__global__ void k_transpose(const float* __restrict__ Wfc, float* __restrict__ WfcT) {
    int i = blockIdx.x * 256 + threadIdx.x;
    if (i < 128 * 416) {
        int u = i / 416, c = i - u * 416;
        WfcT[c * 128 + u] = Wfc[i];
    }
}

// ---------------- Head: maxpool -> conv2 -> FC -> classifier -> log_softmax ----

__global__ __launch_bounds__(128) void k_head(
    const float* __restrict__ y1, const float* __restrict__ k2,
    const float* __restrict__ bk2, const float* __restrict__ WfcT,
    const float* __restrict__ bfc, const float* __restrict__ Wc,
    const float* __restrict__ bc, float* __restrict__ out) {
    __shared__ float yl[1296];       // 81 positions x 16 ch, [p][ch]
    __shared__ float zl[16][41];     // after maxpool, [ch][pos<40], pad
    __shared__ float xr[416];        // conv2 out, index oc*13+t
    __shared__ float k2s[1536];
    __shared__ float fl[128];
    __shared__ float ll[10];
    int t = threadIdx.x;
    int b = blockIdx.x;
    const float* yb = y1 + (size_t)b * 1296;
    for (int i = t; i < 1296; i += 128) yl[i] = yb[i];
    for (int i = t; i < 1536; i += 128) k2s[i] = k2[i];
    __syncthreads();
    // maxpool over position pairs (drop pos 80)
    for (int i = t; i < 640; i += 128) {
        int ic = i & 15, p = i >> 4;
        zl[ic][p] = fmaxf(yl[(2 * p) * 16 + ic], yl[(2 * p + 1) * 16 + ic]);
    }
    __syncthreads();
    // conv2: 32 out-ch x 13 positions, stride 3, k=3
    for (int i = t; i < 416; i += 128) {
        int oc = i / 13, tt = i - oc * 13;
        float acc = bk2[oc];
        for (int ic = 0; ic < 16; ic++) {
            const float* kk = &k2s[(oc * 16 + ic) * 3];
            acc += zl[ic][3 * tt]     * kk[0]
                 + zl[ic][3 * tt + 1] * kk[1]
                 + zl[ic][3 * tt + 2] * kk[2];
        }
        xr[i] = acc;
    }
    __syncthreads();
    // FC 416 -> 128, one thread per output, coalesced WfcT reads
    {
        float acc = bfc[t];
        for (int i = 0; i < 416; i++) acc += xr[i] * WfcT[i * 128 + t];
        fl[t] = fmaxf(acc, 0.f);
    }
    __syncthreads();
    if (t < 10) {
        float acc = bc[t];
        for (int u = 0; u < 128; u++) acc += fl[u] * Wc[t * 128 + u];
        ll[t] = acc;
    }
    __syncthreads();
    if (t < 10) {
        float m = -1e30f;
        for (int c = 0; c < 10; c++) m = fmaxf(m, ll[c]);
        float s = 0.f;
        for (int c = 0; c < 10; c++) s += __expf(ll[c] - m);
        out[b * 10 + t] = ll[t] - m - __logf(s);
    }
}

// ---------------- launch ----------------

extern "C" void kernel_launch(void* const* d_in, const int* in_sizes, int n_in,
                              void* d_out, int out_size, void* d_ws, size_t ws_size,
                              hipStream_t stream) {
    const int*   src   = (const int*)d_in[0];
    const int*   dst   = (const int*)d_in[1];
    const float* w     = (const float*)d_in[2];
    const float* W1    = (const float*)d_in[4];
    const float* b1    = (const float*)d_in[5];
    const float* bias1 = (const float*)d_in[6];
    const float* c1s   = (const float*)d_in[7];
    const float* c1p   = (const float*)d_in[8];
    const float* c1n   = (const float*)d_in[9];
    const float* W2    = (const float*)d_in[10];
    const float* b2    = (const float*)d_in[11];
    const float* bias2 = (const float*)d_in[12];
    const float* c2s   = (const float*)d_in[13];
    const float* c2p   = (const float*)d_in[14];
    const float* c2n   = (const float*)d_in[15];
    const float* k1    = (const float*)d_in[16];
    const float* bk1   = (const float*)d_in[17];
    const float* k2    = (const float*)d_in[18];
    const float* bk2   = (const float*)d_in[19];
    const float* Wfc   = (const float*)d_in[20];
    const float* bfc   = (const float*)d_in[21];
    const float* Wc    = (const float*)d_in[22];
    const float* bc    = (const float*)d_in[23];
    const int E = in_sizes[0];
    const int NT = (E + TE - 1) / TE;
    const int CS = (NT + CH - 1) / CH;

    // workspace carve (256B aligned)
    size_t off = 0;
    auto carve = [&](size_t bytes) -> char* {
        char* p = (char*)d_ws + off;
        off = (off + bytes + 255) & ~(size_t)255;
        return p;
    };
    int*   cnt    = (int*)  carve((size_t)NNODES * 4);
    int*   cntp   = (int*)  carve((size_t)NNODES * 4);
    int*   offs   = (int*)  carve((size_t)NNODES * 4);
    int2*  csrB   = (int2*) carve((size_t)E * 8);
    int*   H      = (int*)  carve((size_t)NT * NBUCK * 4);
    int*   P      = (int*)  carve((size_t)CH * NBUCK * 4);
    int*   T      = (int*)  carve((size_t)NBUCK * 4);
    int*   Bstart = (int*)  carve((size_t)(NBUCK + 1) * 4);
    float* spos   = (float*)carve((size_t)NNODES * 4);
    float* sneg   = (float*)carve((size_t)NNODES * 4);
    unsigned short* h1b = (unsigned short*)carve((size_t)NNODES * 32 * 2);
    unsigned short* hpb = (unsigned short*)carve((size_t)NNODES * 32 * 2);
    unsigned short* hnb = (unsigned short*)carve((size_t)NNODES * 32 * 2);
    float* y1     = (float*)carve((size_t)NNODES * 16 * 4);
    float* WfcT   = (float*)carve((size_t)128 * 416 * 4);
    unsigned short* W2sT = (unsigned short*)carve((size_t)96 * 32 * 2);
    unsigned short* k1T  = (unsigned short*)carve((size_t)64 * 16 * 2);
    (void)ws_size;

    k_hist      <<<NT, 256, 0, stream>>>(dst, H, E);
    k_colA      <<<CH * NBUCK / 256, 256, 0, stream>>>(H, P, NT, CS);
    k_colB      <<<NBUCK / 256, 256, 0, stream>>>(P, T);
    k_colC      <<<CH * NBUCK / 256, 256, 0, stream>>>(H, P, NT, CS);
    k_binscan   <<<1, 256, 0, stream>>>(T, Bstart);
    k_place     <<<NT, 256, 0, stream>>>(src, dst, w, H, Bstart, csrB, E);
    k_sortbucket<<<NBUCK, 256, 0, stream>>>(csrB, Bstart, cnt, cntp, offs);
    k_layer1    <<<NNODES / 8, 256, 0, stream>>>(cnt, cntp, offs, csrB,
                                                 spos, sneg, h1b,
                                                 W1, b1, bias1, c1s, c1p, c1n);
    k_prep      <<<17, 256, 0, stream>>>(W2, c2s, c2p, c2n, k1, W2sT, k1T);
    k_transpose <<<(128 * 416 + 255) / 256, 256, 0, stream>>>(Wfc, WfcT);
    k_agg       <<<NNODES / 8, 256, 0, stream>>>(cnt, cntp, offs, csrB,
                                                 spos, sneg, h1b, hpb, hnb);
    k_mlp_mfma  <<<NNODES / 256, 256, 0, stream>>>(h1b, hpb, hnb, W2sT, k1T,
                                                   b2, bias2, bk1, y1);
    k_head      <<<NGRAPH, 128, 0, stream>>>(y1, k2, bk2, WfcT, bfc, Wc, bc,
                                             (float*)d_out);
}